// Round 3
// baseline (982.392 us; speedup 1.0000x reference)
//
#include <hip/hip_runtime.h>
#include <cstdint>

typedef float float2v __attribute__((ext_vector_type(2)));
typedef _Float16 half2v __attribute__((ext_vector_type(2)));

__device__ inline float2v mk2(float a, float b) { float2v r; r[0] = a; r[1] = b; return r; }

__device__ inline half2v pack2h(float a, float b) {
  return __builtin_bit_cast(half2v, __builtin_amdgcn_cvt_pkrtz(a, b));
}

__device__ inline float fast_exp2(float x) {
#if __has_builtin(__builtin_amdgcn_exp2f)
  return __builtin_amdgcn_exp2f(x);
#else
  return exp2f(x);
#endif
}
__device__ inline float fast_rcp(float x) {
#if __has_builtin(__builtin_amdgcn_rcpf)
  return __builtin_amdgcn_rcpf(x);
#else
  return 1.0f / x;
#endif
}

// lane j gets lane (j^1)'s value, VALU-only (DPP quad_perm [1,0,3,2] = 0xB1)
__device__ inline float dpp_xor1(float v) {
#if __has_builtin(__builtin_amdgcn_update_dpp)
  int r = __builtin_amdgcn_update_dpp(0, __builtin_bit_cast(int, v), 0xB1, 0xF, 0xF, true);
  return __builtin_bit_cast(float, r);
#elif __has_builtin(__builtin_amdgcn_mov_dpp)
  int r = __builtin_amdgcn_mov_dpp(__builtin_bit_cast(int, v), 0xB1, 0xF, 0xF, true);
  return __builtin_bit_cast(float, r);
#else
  return __shfl_xor(v, 1, 64);
#endif
}

__device__ inline float dot2_acc(half2v a, half2v b, float c) {
#if __has_builtin(__builtin_amdgcn_fdot2)
  return __builtin_amdgcn_fdot2(a, b, c, false);
#else
  c = fmaf((float)a[0], (float)b[0], c);
  return fmaf((float)a[1], (float)b[1], c);
#endif
}

#define BB 256
#define SS 4096
#define II 32
#define HH 64

// ---------------- prep: Wc = W_ih @ W_in  [64][32], bc = W_ih@b_in + bias ----------------
__global__ __launch_bounds__(256) void prep_kernel(
    const float* __restrict__ W_in, const float* __restrict__ b_in,
    const float* __restrict__ W_ih, const float* __restrict__ bias,
    float* __restrict__ Wc, float* __restrict__ bc) {
  int tid = threadIdx.x;
  int j = tid & 63;
  int iq = tid >> 6;
  float acc[8];
#pragma unroll
  for (int i = 0; i < 8; ++i) acc[i] = 0.f;
  const float* wih = W_ih + j * HH;
  for (int h = 0; h < HH; ++h) {
    float w = wih[h];
    const float* wr = W_in + h * II + iq * 8;
#pragma unroll
    for (int i = 0; i < 8; ++i) acc[i] = fmaf(w, wr[i], acc[i]);
  }
#pragma unroll
  for (int i = 0; i < 8; ++i) Wc[j * II + iq * 8 + i] = acc[i];
  if (iq == 0) {
    float s = 0.f;
    for (int h = 0; h < HH; ++h) s = fmaf(wih[h], b_in[h], s);
    bc[j] = s + bias[j];
  }
}

// ---------------- gemm: pre[row][j] = x[row] . Wc[j] + bc[j]  (f16 out) ----------------
__global__ __launch_bounds__(256) void gemm_pre_kernel(
    const float* __restrict__ x, const float* __restrict__ Wc,
    const float* __restrict__ bc, _Float16* __restrict__ pre) {
  __shared__ __align__(16) float xbuf[64 * II];
  int tid = threadIdx.x;
  int lane = tid & 63;
  int wave = tid >> 6;
  long rowbase = (long)blockIdx.x * 64;
  const float4* xg = (const float4*)(x + rowbase * II);
  float4* xb = (float4*)xbuf;
  xb[tid] = xg[tid];
  xb[tid + 256] = xg[tid + 256];
  float2v w2[16];
  {
    const float4* wr = (const float4*)(Wc + lane * II);
#pragma unroll
    for (int i = 0; i < 8; ++i) {
      float4 q = wr[i];
      w2[2 * i] = mk2(q.x, q.y);
      w2[2 * i + 1] = mk2(q.z, q.w);
    }
  }
  float bcv = bc[lane];
  __syncthreads();
  _Float16* pb = pre + (rowbase + wave * 16) * HH + lane;
#pragma unroll 4
  for (int rr = 0; rr < 16; ++rr) {
    const float4* xr = (const float4*)(xbuf + (wave * 16 + rr) * II);
    float2v a0 = mk2(0, 0), a1 = mk2(0, 0), a2 = mk2(0, 0), a3 = mk2(0, 0);
#pragma unroll
    for (int i = 0; i < 8; i += 2) {
      float4 q = xr[i];
      float4 p = xr[i + 1];
      a0 += mk2(q.x, q.y) * w2[2 * i];
      a1 += mk2(q.z, q.w) * w2[2 * i + 1];
      a2 += mk2(p.x, p.y) * w2[2 * i + 2];
      a3 += mk2(p.z, p.w) * w2[2 * i + 3];
    }
    float2v aa = (a0 + a1) + (a2 + a3);
    pb[(long)rr * HH] = (_Float16)(aa[0] + aa[1] + bcv);
  }
}

// ---------------- scan: one wave per batch; SGPR-broadcast GEMV, no LDS on the chain ----------------
__global__ __launch_bounds__(64) void scan_kernel(
    const float* __restrict__ W_hh, const float* __restrict__ tau,
    const float* __restrict__ W_out, const float* __restrict__ b_out,
    const _Float16* __restrict__ pre, float* __restrict__ out) {
  __shared__ __align__(16) float tbuf[64 * 68];            // tanh(h) per chunk (output GEMV only, off-chain)
  __shared__ __align__(16) _Float16 prebuf[2][64 * HH];    // double-buffered pre chunks (f16)
  __shared__ __align__(16) float woutl[64];
  int lane = threadIdx.x;
  int b = blockIdx.x;
  // W_hh row j as 32 packed f16 pairs: wph[m] = (W[j][2m], W[j][2m+1])
  half2v wph[32];
  {
    const float4* wr = (const float4*)(W_hh + lane * HH);
#pragma unroll
    for (int i = 0; i < 16; ++i) {
      float4 q = wr[i];
      wph[2 * i] = pack2h(q.x, q.y);
      wph[2 * i + 1] = pack2h(q.z, q.w);
    }
  }
  float cinv = 1.0f / tau[lane];  // dt = 1.0
  float aco = 1.0f - cinv;
  woutl[lane] = W_out[lane];
  float bout = b_out[0];
  const _Float16* preb = pre + (size_t)b * (SS * HH);
  float* outb = out + (size_t)b * SS;
  // prologue: chunk 0 -> LDS (8 KB)
  {
    const float4* src = (const float4*)preb;
    float4* dst = (float4*)prebuf[0];
#pragma unroll
    for (int k = 0; k < 8; ++k) dst[k * 64 + lane] = src[k * 64 + lane];
  }
  float h = 0.0f;
  half2v pk;  // packed (t_j, t_{j^1}); even lanes hold pair (t_{2m}, t_{2m+1}); t_{-1} = 0
  pk[0] = (_Float16)0.f; pk[1] = (_Float16)0.f;
  int cur = 0;
  float pvc = (float)prebuf[0][lane];  // pre for step 0
  for (int c = 0; c < 64; ++c) {
    // register-prefetch next chunk (overlaps the 64 compute steps)
    float4 nxt[8];
    if (c < 63) {
      const float4* src = (const float4*)(preb + (size_t)(c + 1) * (64 * HH));
#pragma unroll
      for (int k = 0; k < 8; ++k) nxt[k] = src[k * 64 + lane];
    }
    const _Float16* ph = prebuf[cur];
#pragma unroll 8
    for (int r = 0; r < 64; ++r) {
      // --- GEMV via SGPR broadcast: 32 readlanes of packed pairs + 32 dot2 ---
      int pkb = __builtin_bit_cast(int, pk);
      float a0 = 0.f, a1 = 0.f, a2 = 0.f, a3 = 0.f;
#pragma unroll
      for (int m = 0; m < 32; m += 4) {
        int s0 = __builtin_amdgcn_readlane(pkb, 2 * m);
        int s1 = __builtin_amdgcn_readlane(pkb, 2 * m + 2);
        int s2 = __builtin_amdgcn_readlane(pkb, 2 * m + 4);
        int s3 = __builtin_amdgcn_readlane(pkb, 2 * m + 6);
        a0 = dot2_acc(wph[m], __builtin_bit_cast(half2v, s0), a0);
        a1 = dot2_acc(wph[m + 1], __builtin_bit_cast(half2v, s1), a1);
        a2 = dot2_acc(wph[m + 2], __builtin_bit_cast(half2v, s2), a2);
        a3 = dot2_acc(wph[m + 3], __builtin_bit_cast(half2v, s3), a3);
      }
      float dot = (a0 + a1) + (a2 + a3);
      // --- h update ---
      h = fmaf(aco, h, cinv * (dot + pvc));
      // prefetch next step's pre (off-chain: only feeds the NEXT h update)
      if (r < 63) pvc = (float)ph[(r + 1) * HH + lane];
      // --- tanh(h) = 1 - 2/(exp2(2*log2e*h)+1) ---
      float e = fast_exp2(h * 2.885390081777927f);
      float tv = 1.0f - 2.0f * fast_rcp(e + 1.0f);
      // store for output GEMV (nothing on the chain reads this)
      tbuf[r * 68 + lane] = tv;
      // --- pack (t_j, t_{j^1}) as half2 for next step's broadcast (VALU-only) ---
      float to = dpp_xor1(tv);
      pk = pack2h(tv, to);
    }
    // fused output GEMV for this chunk: lane = step index within chunk
    {
      const float4* tr = (const float4*)(tbuf + lane * 68);
      const float4* wl = (const float4*)woutl;
      float2v s0 = mk2(0, 0), s1 = mk2(0, 0);
#pragma unroll
      for (int i = 0; i < 16; ++i) {
        float4 q = tr[i];
        float4 w = wl[i];
        s0 += mk2(q.x, q.y) * mk2(w.x, w.y);
        s1 += mk2(q.z, q.w) * mk2(w.z, w.w);
      }
      float2v ss = s0 + s1;
      outb[c * 64 + lane] = ss[0] + ss[1] + bout;
    }
    // stage prefetched chunk into the other LDS buffer, then load next pvc
    if (c < 63) {
      float4* dst = (float4*)prebuf[cur ^ 1];
#pragma unroll
      for (int k = 0; k < 8; ++k) dst[k * 64 + lane] = nxt[k];
      cur ^= 1;
      pvc = (float)prebuf[cur][lane];  // step 0 of next chunk
    }
  }
}

extern "C" void kernel_launch(void* const* d_in, const int* in_sizes, int n_in,
                              void* d_out, int out_size, void* d_ws, size_t ws_size,
                              hipStream_t stream) {
  const float* x     = (const float*)d_in[0];
  const float* W_in  = (const float*)d_in[1];
  const float* b_in  = (const float*)d_in[2];
  const float* W_hh  = (const float*)d_in[3];
  const float* W_ih  = (const float*)d_in[4];
  const float* bias  = (const float*)d_in[5];
  const float* tau   = (const float*)d_in[6];
  const float* W_out = (const float*)d_in[7];
  const float* b_out = (const float*)d_in[8];
  float* out = (float*)d_out;
  char* ws = (char*)d_ws;
  float* Wc = (float*)ws;                    // 8 KB
  float* bc = (float*)(ws + 8192);           // 256 B
  _Float16* pre = (_Float16*)(ws + 16384);   // 64 MiB f16 [B*S][64]

  hipLaunchKernelGGL(prep_kernel, dim3(1), dim3(256), 0, stream,
                     W_in, b_in, W_ih, bias, Wc, bc);
  hipLaunchKernelGGL(gemm_pre_kernel, dim3(16384), dim3(256), 0, stream,
                     x, Wc, bc, pre);
  hipLaunchKernelGGL(scan_kernel, dim3(BB), dim3(64), 0, stream,
                     W_hh, tau, W_out, b_out, pre, out);
}